// Round 6
// baseline (501.022 us; speedup 1.0000x reference)
//
#include <hip/hip_runtime.h>
#include <hip/hip_fp16.h>
#include <math.h>

#define HD 256
#define NHEAD 4
#define CH 64
#define NLAYER 3
#define NEG_SLOPE 0.2f

typedef __attribute__((ext_vector_type(8))) _Float16 half8;
typedef __attribute__((ext_vector_type(4))) _Float16 half4v;
typedef __attribute__((ext_vector_type(4))) float float4v;
typedef __attribute__((ext_vector_type(4))) unsigned uint4v;

// ---------------------------------------------------------------------------
// FUSED: node embed (blocks [0, embedBlocks)) + degree count (rest).
// ---------------------------------------------------------------------------
__global__ __launch_bounds__(256) void embed_count_kernel(
    const float* __restrict__ x, const float* __restrict__ Wn,
    const float* __restrict__ bn_b, _Float16* __restrict__ h, int N,
    const int* __restrict__ col, int* __restrict__ deg, int E,
    int embedBlocks) {
  int tid = threadIdx.x;
  if ((int)blockIdx.x < embedBlocks) {
    int base = blockIdx.x * 8;
    __shared__ float xs[8][9];
    int nn = N - base;
    if (nn > 8) nn = 8;
    if (tid < nn * 9) xs[tid / 9][tid % 9] = x[(size_t)base * 9 + tid];
    __syncthreads();
    float b = bn_b[tid];
    for (int i = 0; i < nn; ++i) {
      float v = b;
#pragma unroll
      for (int k = 0; k < 9; ++k) v += xs[i][k] * Wn[k * HD + tid];
      h[(size_t)(base + i) * HD + tid] = (_Float16)v;
    }
  } else {
    int e = (blockIdx.x - embedBlocks) * 256 + tid;
    if (e < E) atomicAdd(&deg[col[e]], 1);
  }
}

// ---------------------------------------------------------------------------
// FUSED: precompute_wc (blocks 0..11) + conv_bfrag (blocks 12..).
// ---------------------------------------------------------------------------
__global__ __launch_bounds__(256) void wc_bfrag_kernel(
    const float* __restrict__ lin_edge_w, const float* __restrict__ att_edge,
    const float* __restrict__ We, const float* __restrict__ be_b,
    float* __restrict__ Wc, float* __restrict__ bc,
    const float* __restrict__ lin_w, _Float16* __restrict__ Bf_hi) {
  int tid = threadIdx.x;
  if (blockIdx.x < 12) {
    int lh = blockIdx.x;           // l*4+hh
    int l = lh >> 2, hh = lh & 3;
    __shared__ float weff[256];
    int j = tid;
    const float* lw = lin_edge_w + (size_t)l * HD * HD + (size_t)j * HD + hh * CH;
    const float* ae = att_edge + l * HD + hh * CH;
    float s = 0.f;
#pragma unroll 8
    for (int c = 0; c < CH; ++c) s += lw[c] * ae[c];
    weff[j] = s;
    __syncthreads();
    if (j < 5) {
      float acc = 0.f;
      for (int t = 0; t < 256; ++t) acc += We[j * HD + t] * weff[t];
      Wc[j * 12 + lh] = acc;
    } else if (j == 5) {
      float acc = 0.f;
      for (int t = 0; t < 256; ++t) acc += be_b[t] * weff[t];
      bc[lh] = acc;
    }
  } else {
    int bid = (blockIdx.x - 12) * 4 + (tid >> 6);  // l*128 + kt*16 + ntg
    int l = bid >> 7;
    int kt = (bid >> 4) & 7, ntg = bid & 15;
    int lane = tid & 63;
    const float* B = lin_w + (size_t)l * HD * HD;
    size_t base = ((size_t)bid * 64 + lane) * 8;
    int k0 = kt * 32 + (lane >> 4) * 8;
    int n = ((ntg >= 8) ? 128 : 0) + (lane & 15) * 8 + (ntg & 7);
#pragma unroll
    for (int j = 0; j < 8; ++j) {
      Bf_hi[base + j] = (_Float16)B[(size_t)(k0 + j) * HD + n];
    }
  }
}

// ---------------------------------------------------------------------------
// CSR scan kernels
// ---------------------------------------------------------------------------
__global__ __launch_bounds__(256) void tile_sums_kernel(
    const int* __restrict__ deg, int* __restrict__ tsum, int N) {
  __shared__ int red[256];
  int i = blockIdx.x * 256 + threadIdx.x;
  red[threadIdx.x] = (i < N) ? deg[i] : 0;
  __syncthreads();
  for (int off = 128; off > 0; off >>= 1) {
    if (threadIdx.x < off) red[threadIdx.x] += red[threadIdx.x + off];
    __syncthreads();
  }
  if (threadIdx.x == 0) tsum[blockIdx.x] = red[0];
}

__global__ __launch_bounds__(64) void scan_tsums_kernel(
    const int* __restrict__ tsum, int* __restrict__ toff, int T) {
  int lane = threadIdx.x;
  int carry = 0;
  for (int base = 0; base < T; base += 64) {
    int i = base + lane;
    int orig = (i < T) ? tsum[i] : 0;
    int v = orig;
#pragma unroll
    for (int off = 1; off < 64; off <<= 1) {
      int t = __shfl_up(v, off, 64);
      if (lane >= off) v += t;
    }
    if (i < T) toff[i] = carry + v - orig;
    carry += __shfl(v, 63, 64);
  }
}

__global__ __launch_bounds__(256) void scan_local_kernel(
    const int* __restrict__ deg, const int* __restrict__ toff,
    int* __restrict__ row_start, int N, int E) {
  __shared__ int buf[256];
  int i = blockIdx.x * 256 + threadIdx.x;
  int v = (i < N) ? deg[i] : 0;
  buf[threadIdx.x] = v;
  __syncthreads();
  for (int off = 1; off < 256; off <<= 1) {
    int t = (threadIdx.x >= off) ? buf[threadIdx.x - off] : 0;
    __syncthreads();
    buf[threadIdx.x] += t;
    __syncthreads();
  }
  if (i < N) row_start[i] = toff[blockIdx.x] + buf[threadIdx.x] - v;
  if (blockIdx.x == 0 && threadIdx.x == 0) row_start[N] = E;
}

// ---------------------------------------------------------------------------
// R6 scatter phase A — DEPOSIT: slot assignment only. One scattered 4B
// write per edge (eid[slot] = e). 16 writes per 64B line merge in L2 —
// far less RMW volume than scattering the 48B payload (R4: 102MB WRITE).
// ---------------------------------------------------------------------------
__global__ __launch_bounds__(256) void deposit_kernel(
    const int* __restrict__ col, const int* __restrict__ row_start,
    int* __restrict__ cursor, int* __restrict__ eid, int E) {
  int e = blockIdx.x * 256 + threadIdx.x;
  if (e >= E) return;
  int c = col[e];
  int p = atomicAdd(&cursor[c], 1);
  eid[row_start[c] + p] = e;
}

// ---------------------------------------------------------------------------
// R6 scatter phase B — BUILD: slot-parallel. Reads eid densely, gathers
// row[e] + edge_attr[e] (scattered READS — no RMW, L3-resident), computes
// the 12 ae values, writes three per-layer 16B records DENSELY (full-line
// coalesced). Aggregate (runs 3x) gets its optimal dense layout back
// (R4: 67.7us, FETCH 213MB) while the writer streams at full line rate.
// ---------------------------------------------------------------------------
__global__ __launch_bounds__(256) void build_records_kernel(
    const int* __restrict__ eid, const int* __restrict__ row,
    const float* __restrict__ edge_attr, const float* __restrict__ Wc,
    const float* __restrict__ bc, unsigned* __restrict__ ecsr, int E) {
  __shared__ float sWc[60];
  __shared__ float sbc[12];
  int t = threadIdx.x;
  if (t < 60) sWc[t] = Wc[t];
  if (t < 12) sbc[t] = bc[t];
  __syncthreads();
  int s = blockIdx.x * 256 + t;
  if (s >= E) return;
  int e = eid[s];
  unsigned r0 = (unsigned)row[e];
  float ea[5];
#pragma unroll
  for (int k = 0; k < 5; ++k) ea[k] = edge_attr[(size_t)e * 5 + k];
  size_t E4 = (size_t)E * 4;  // per-layer region stride in unsigned words
#pragma unroll
  for (int l = 0; l < NLAYER; ++l) {
    float av[NHEAD];
#pragma unroll
    for (int hh = 0; hh < NHEAD; ++hh) {
      int lh = l * NHEAD + hh;
      float sum = sbc[lh];
#pragma unroll
      for (int k = 0; k < 5; ++k) sum += ea[k] * sWc[k * 12 + lh];
      av[hh] = sum;
    }
    __half2 p0 = __floats2half2_rn(av[0], av[1]);
    __half2 p1 = __floats2half2_rn(av[2], av[3]);
    uint4v v = {r0, *(unsigned*)&p0, *(unsigned*)&p1, 0u};
    *(uint4v*)(ecsr + l * E4 + (size_t)s * 4) = v;
  }
}

// ---------------------------------------------------------------------------
// MFMA GEMM — A fp16: direct half8 load, 1 MFMA per (kt,nt).
// Head-split grid y, 8KB LDS B-stage.
// ---------------------------------------------------------------------------
__global__ __launch_bounds__(512) void mfma_gemm_fused_kernel(
    const _Float16* __restrict__ A, const _Float16* __restrict__ Bf_hi,
    const float* __restrict__ att_s, const float* __restrict__ att_d,
    __half* __restrict__ xh_h, float* __restrict__ a_src,
    float* __restrict__ a_dst, int N) {
  __shared__ _Float16 sBh[4096];  // 8 KB: kt-slice of this block's col half
  const int tid = threadIdx.x;
  const int wave = tid >> 6, lane = tid & 63;
  const int m = lane & 15, quad = lane >> 4;
  const int y = blockIdx.y;
  const int rowbase = blockIdx.x * 128 + wave * 16;
  const int arow = rowbase + m;
  const int arowc = (arow < N) ? arow : (N - 1);

  float4v acc[8];
#pragma unroll
  for (int nt = 0; nt < 8; ++nt) acc[nt] = (float4v){0.f, 0.f, 0.f, 0.f};

  for (int kt = 0; kt < 8; ++kt) {
    __syncthreads();  // previous iteration's LDS reads done
    {
      const float4* gh = (const float4*)(Bf_hi + ((size_t)kt * 16 + y * 8) * 512);
      ((float4*)sBh)[tid] = gh[tid];
    }
    half8 a = *(const half8*)(A + (size_t)arowc * HD + kt * 32 + quad * 8);
    __syncthreads();  // staging complete
#pragma unroll
    for (int nt = 0; nt < 8; ++nt) {
      half8 bhi = *(const half8*)&sBh[nt * 512 + lane * 8];
      acc[nt] = __builtin_amdgcn_mfma_f32_16x16x32_f16(a, bhi, acc[nt], 0, 0, 0);
    }
  }

  // lane's 8 cols: y*128 + m*8 + nt — all in head hh = y*2 + (m>>3)
  const int hh = y * 2 + (m >> 3);
  const int colbase = y * 128 + m * 8;
  float ats[8], atd[8];
#pragma unroll
  for (int nt = 0; nt < 8; ++nt) {
    ats[nt] = att_s[colbase + nt];
    atd[nt] = att_d[colbase + nt];
  }
  _Float16* xf = (_Float16*)xh_h;
#pragma unroll
  for (int r = 0; r < 4; ++r) {
    int orow = rowbase + quad * 4 + r;
    bool valid = orow < N;
    float ps = 0.f, pd = 0.f;
    half8 h0;
#pragma unroll
    for (int nt = 0; nt < 8; ++nt) {
      h0[nt] = (_Float16)acc[nt][r];
      ps += acc[nt][r] * ats[nt];
      pd += acc[nt][r] * atd[nt];
    }
    if (valid) {
      *(half8*)(xf + (size_t)orow * HD + colbase) = h0;
    }
    ps += __shfl_xor(ps, 1, 64);
    ps += __shfl_xor(ps, 2, 64);
    ps += __shfl_xor(ps, 4, 64);
    pd += __shfl_xor(pd, 1, 64);
    pd += __shfl_xor(pd, 2, 64);
    pd += __shfl_xor(pd, 4, 64);
    if (valid && (m & 7) == 0) {
      a_src[(size_t)orow * NHEAD + hh] = ps;
      a_dst[(size_t)orow * NHEAD + hh] = pd;
    }
  }
}

// ---------------------------------------------------------------------------
// SINGLE-PASS fused softmax + gather-aggregate, 2 nodes/wave (lanes 0-31 =
// node A, 32-63 = node B; 8 ch/lane). R4 structure restored verbatim:
// ZERO cross-lane ops in the inner loop; dense per-layer 16B records
// (uniform dwordx4 per edge → TA broadcast); all 8 weights computed
// locally per lane. (R4: 67.7us, VALU 54.6% — best measured.)
// ---------------------------------------------------------------------------
__global__ __launch_bounds__(256) void fused_aggregate_kernel(
    const __half* __restrict__ xh_h, const unsigned* __restrict__ elay,
    const int* __restrict__ row_start,
    const float* __restrict__ a_src, const float* __restrict__ a_dst,
    const float* __restrict__ cb, const float* __restrict__ gm,
    const float* __restrict__ bt, float inv_std, _Float16* __restrict__ hout,
    int N) {
  const int tid = threadIdx.x;
  const int lane = tid & 63;
  const int wave = tid >> 6;
  const int halfw = lane >> 5;      // 0: node A, 1: node B
  const int l32 = lane & 31;        // index within half-wave
  const int hw = l32 >> 3;          // head 0..3
  const int chb = l32 * 8;          // channel base (8 ch per lane)
  const char* __restrict__ xb = (const char*)xh_h;
  const char* __restrict__ eb = (const char*)elay;
  const char* __restrict__ ab = (const char*)a_src;
  const bool hi_half = (hw & 1);
  const int awsel = (hw >> 1);      // 0 → word1 (heads 0,1), 1 → word2 (heads 2,3)

  int n = blockIdx.x * 8 + wave * 2 + halfw;
  bool valid = n < N;
  int nc = valid ? n : (N - 1);

  int s = row_start[nc];
  int e = row_start[nc + 1];
  if (!valid) e = s;

  // self row (8 ch = 16B) + dst logit — issued early
  half8 sv = *(const half8*)(xb + ((unsigned)nc << 9) + ((unsigned)l32 << 4));
  float based = a_dst[(size_t)nc * 4 + hw];

  float acc[8];
#pragma unroll
  for (int k = 0; k < 8; ++k) acc[k] = 0.f;
  float zpart = 0.f, aepart = 0.f;

  for (int chunk = s; chunk < e; chunk += 8) {
    // 8 record loads (16B each; uniform address within half-wave)
    uint4v rc[8];
#pragma unroll
    for (int u = 0; u < 8; ++u) {
      int ed = chunk + u;
      ed = (ed < e) ? ed : (e - 1);   // clamp: stays within [s,e)
      rc[u] = *(const uint4v*)(eb + ((size_t)(unsigned)ed << 4));
    }
    unsigned rows[8], aw[8];
#pragma unroll
    for (int u = 0; u < 8; ++u) {
      rows[u] = rc[u][0];
      aw[u] = awsel ? rc[u][2] : rc[u][1];
    }
    // 8 channel gathers (16B/lane, 512B per half-wave) — independent of the
    // weight chain below; both ladders stay in flight together.
    half8 xr[8];
#pragma unroll
    for (int u = 0; u < 8; ++u)
      xr[u] = *(const half8*)(xb + (((size_t)rows[u] << 9) +
                                    ((unsigned)l32 << 4)));
    // weights: each lane computes all 8 locally (no broadcast needed)
    float w[8];
#pragma unroll
    for (int u = 0; u < 8; ++u) {
      __half2 h2 = *(__half2*)&aw[u];
      float ae = hi_half ? __high2float(h2) : __low2float(h2);
      float as_ = *(const float*)(ab + ((size_t)rows[u] << 4) +
                                  ((unsigned)hw << 2));
      float lg = as_ + based + ae;
      lg = (lg >= 0.f) ? lg : NEG_SLOPE * lg;
      float ww = __expf(lg);
      bool mv = (chunk + u) < e;
      ww = mv ? ww : 0.f;
      ae = mv ? ae : 0.f;
      zpart += ww;
      aepart += ae;
      w[u] = ww;
    }
    // consume
#pragma unroll
    for (int u = 0; u < 8; ++u) {
#pragma unroll
      for (int k = 0; k < 8; ++k) acc[k] += w[u] * (float)xr[u][k];
    }
  }

  float dinv = (e > s) ? 1.0f / (float)(e - s) : 1.0f;
  float sl = *(const float*)(ab + ((unsigned)nc << 4) + ((unsigned)hw << 2))
             + based + aepart * dinv;
  sl = (sl >= 0.f) ? sl : NEG_SLOPE * sl;
  float wself = __expf(sl);
#pragma unroll
  for (int k = 0; k < 8; ++k) acc[k] += wself * (float)sv[k];
  float zinv = 1.0f / (zpart + wself + 1e-16f);

  if (valid) {
    half8 ho;
#pragma unroll
    for (int k = 0; k < 8; ++k) {
      float gsk = gm[chb + k] * inv_std;
      float ofk = cb[chb + k] * gsk + bt[chb + k];
      ho[k] = (_Float16)fmaxf(acc[k] * zinv * gsk + ofk, 0.f);
    }
    *(half8*)&hout[(size_t)n * HD + chb] = ho;
  }
}

// ---------------------------------------------------------------------------
// Global mean pool over sorted batch ids (h fp16). One block per graph,
// half2 loads + 4-deep independent accumulators.
// ---------------------------------------------------------------------------
__global__ __launch_bounds__(128) void pool_kernel(
    const _Float16* __restrict__ h, const int* __restrict__ batch,
    float* __restrict__ out, int N) {
  int g = blockIdx.x;
  int tid = threadIdx.x;
  __shared__ int s_lo, s_hi;
  if (tid == 0) {
    int lo = 0, hi = N;
    while (lo < hi) { int mid = (lo + hi) >> 1; if (batch[mid] < g) lo = mid + 1; else hi = mid; }
    s_lo = lo;
    lo = 0; hi = N;
    while (lo < hi) { int mid = (lo + hi) >> 1; if (batch[mid] < g + 1) lo = mid + 1; else hi = mid; }
    s_hi = lo;
  }
  __syncthreads();
  int lo = s_lo, hi = s_hi;
  const __half2* h2 = (const __half2*)h;  // N rows x 128 half2
  float a0 = 0.f, b0 = 0.f, a1 = 0.f, b1 = 0.f;
  float a2 = 0.f, b2 = 0.f, a3 = 0.f, b3 = 0.f;
  int n = lo;
  for (; n + 4 <= hi; n += 4) {
    __half2 v0 = h2[(size_t)(n + 0) * 128 + tid];
    __half2 v1 = h2[(size_t)(n + 1) * 128 + tid];
    __half2 v2 = h2[(size_t)(n + 2) * 128 + tid];
    __half2 v3 = h2[(size_t)(n + 3) * 128 + tid];
    a0 += __low2float(v0); b0 += __high2float(v0);
    a1 += __low2float(v1); b1 += __high2float(v1);
    a2 += __low2float(v2); b2 += __high2float(v2);
    a3 += __low2float(v3); b3 += __high2float(v3);
  }
  for (; n < hi; ++n) {
    __half2 v = h2[(size_t)n * 128 + tid];
    a0 += __low2float(v); b0 += __high2float(v);
  }
  float sa = (a0 + a1) + (a2 + a3);
  float sb = (b0 + b1) + (b2 + b3);
  int cnt = hi - lo;
  float inv = 1.0f / (float)(cnt > 0 ? cnt : 1);
  float2 o;
  o.x = sa * inv;
  o.y = sb * inv;
  *(float2*)&out[(size_t)g * HD + tid * 2] = o;
}

// ---------------------------------------------------------------------------
extern "C" void kernel_launch(void* const* d_in, const int* in_sizes, int n_in,
                              void* d_out, int out_size, void* d_ws, size_t ws_size,
                              hipStream_t stream) {
  const float* x = (const float*)d_in[0];
  const int* ei = (const int*)d_in[1];
  const float* edge_attr = (const float*)d_in[2];
  const int* batch = (const int*)d_in[3];
  const float* Wn = (const float*)d_in[4];
  const float* bn_b = (const float*)d_in[5];
  const float* We = (const float*)d_in[6];
  const float* be_b = (const float*)d_in[7];
  const float* lin_w = (const float*)d_in[8];
  const float* att_src = (const float*)d_in[9];
  const float* att_dst = (const float*)d_in[10];
  const float* lin_edge_w = (const float*)d_in[11];
  const float* att_edge = (const float*)d_in[12];
  const float* conv_bias = (const float*)d_in[13];
  const float* gamma = (const float*)d_in[14];
  const float* beta = (const float*)d_in[15];

  const int N = in_sizes[3];
  const int E = in_sizes[1] / 2;
  const int G = out_size / HD;
  const int* row = ei;
  const int* col = ei + E;

  char* ws = (char*)d_ws;
  size_t off = 0;
  auto alloc = [&](size_t bytes) -> char* {
    char* p = ws + off;
    off += (bytes + 255) & ~(size_t)255;
    return p;
  };
  _Float16* h = (_Float16*)alloc((size_t)N * HD * 2);
  __half* xh_h = (__half*)alloc((size_t)N * HD * 2);
  float* a_src = (float*)alloc((size_t)N * NHEAD * 4);
  float* a_dst = (float*)alloc((size_t)N * NHEAD * 4);
  unsigned* ecsr = (unsigned*)alloc((size_t)E * 16 * NLAYER);  // 16B/edge/layer
  int* eid = (int*)alloc((size_t)E * 4);
  int* deg = (int*)alloc((size_t)N * 4);
  int* row_start = (int*)alloc((size_t)(N + 1) * 4);
  int* cursor = (int*)alloc((size_t)N * 4);
  int* tsum = (int*)alloc(4096);
  int* toff = (int*)alloc(4096);
  float* Wc = (float*)alloc(64 * 4);
  float* bc = (float*)alloc(16 * 4);
  _Float16* Bf_hi = (_Float16*)alloc((size_t)NLAYER * HD * HD * 2);

  (void)hipMemsetAsync(deg, 0, (size_t)N * 4, stream);
  (void)hipMemsetAsync(cursor, 0, (size_t)N * 4, stream);

  int embedBlocks = (N + 7) / 8;
  int countBlocks = (E + 255) / 256;
  embed_count_kernel<<<embedBlocks + countBlocks, 256, 0, stream>>>(
      x, Wn, bn_b, h, N, col, deg, E, embedBlocks);
  wc_bfrag_kernel<<<12 + NLAYER * 32, 256, 0, stream>>>(
      lin_edge_w, att_edge, We, be_b, Wc, bc, lin_w, Bf_hi);
  int T = (N + 255) / 256;
  tile_sums_kernel<<<T, 256, 0, stream>>>(deg, tsum, N);
  scan_tsums_kernel<<<1, 64, 0, stream>>>(tsum, toff, T);
  scan_local_kernel<<<T, 256, 0, stream>>>(deg, toff, row_start, N, E);
  deposit_kernel<<<(E + 255) / 256, 256, 0, stream>>>(
      col, row_start, cursor, eid, E);
  build_records_kernel<<<(E + 255) / 256, 256, 0, stream>>>(
      eid, row, edge_attr, Wc, bc, ecsr, E);

  const float inv_std = 1.0f / sqrtf(1.0f + 1e-5f);
  for (int l = 0; l < NLAYER; ++l) {
    dim3 gg((N + 127) / 128, 2);
    mfma_gemm_fused_kernel<<<gg, 512, 0, stream>>>(
        h, Bf_hi + (size_t)l * HD * HD,
        att_src + l * HD, att_dst + l * HD, xh_h, a_src, a_dst, N);
    fused_aggregate_kernel<<<(N + 7) / 8, 256, 0, stream>>>(
        xh_h, ecsr + (size_t)l * E * 4, row_start, a_src, a_dst,
        conv_bias + l * HD, gamma + l * HD, beta + l * HD, inv_std, h, N);
  }
  pool_kernel<<<G, 128, 0, stream>>>(h, batch, (float*)d_out, N);
}

// Round 7
// 472.299 us; speedup vs baseline: 1.0608x; 1.0608x over previous
//
#include <hip/hip_runtime.h>
#include <hip/hip_fp16.h>
#include <math.h>

#define HD 256
#define NHEAD 4
#define CH 64
#define NLAYER 3
#define NEG_SLOPE 0.2f

typedef __attribute__((ext_vector_type(8))) _Float16 half8;
typedef __attribute__((ext_vector_type(4))) _Float16 half4v;
typedef __attribute__((ext_vector_type(4))) float float4v;
typedef __attribute__((ext_vector_type(4))) unsigned uint4v;

// ---------------------------------------------------------------------------
// FUSED: node embed (blocks [0, embedBlocks)) + degree count (rest).
// ---------------------------------------------------------------------------
__global__ __launch_bounds__(256) void embed_count_kernel(
    const float* __restrict__ x, const float* __restrict__ Wn,
    const float* __restrict__ bn_b, _Float16* __restrict__ h, int N,
    const int* __restrict__ col, int* __restrict__ deg, int E,
    int embedBlocks) {
  int tid = threadIdx.x;
  if ((int)blockIdx.x < embedBlocks) {
    int base = blockIdx.x * 8;
    __shared__ float xs[8][9];
    int nn = N - base;
    if (nn > 8) nn = 8;
    if (tid < nn * 9) xs[tid / 9][tid % 9] = x[(size_t)base * 9 + tid];
    __syncthreads();
    float b = bn_b[tid];
    for (int i = 0; i < nn; ++i) {
      float v = b;
#pragma unroll
      for (int k = 0; k < 9; ++k) v += xs[i][k] * Wn[k * HD + tid];
      h[(size_t)(base + i) * HD + tid] = (_Float16)v;
    }
  } else {
    int e = (blockIdx.x - embedBlocks) * 256 + tid;
    if (e < E) atomicAdd(&deg[col[e]], 1);
  }
}

// ---------------------------------------------------------------------------
// FUSED: precompute_wc (blocks 0..11) + conv_bfrag (blocks 12..).
// ---------------------------------------------------------------------------
__global__ __launch_bounds__(256) void wc_bfrag_kernel(
    const float* __restrict__ lin_edge_w, const float* __restrict__ att_edge,
    const float* __restrict__ We, const float* __restrict__ be_b,
    float* __restrict__ Wc, float* __restrict__ bc,
    const float* __restrict__ lin_w, _Float16* __restrict__ Bf_hi) {
  int tid = threadIdx.x;
  if (blockIdx.x < 12) {
    int lh = blockIdx.x;           // l*4+hh
    int l = lh >> 2, hh = lh & 3;
    __shared__ float weff[256];
    int j = tid;
    const float* lw = lin_edge_w + (size_t)l * HD * HD + (size_t)j * HD + hh * CH;
    const float* ae = att_edge + l * HD + hh * CH;
    float s = 0.f;
#pragma unroll 8
    for (int c = 0; c < CH; ++c) s += lw[c] * ae[c];
    weff[j] = s;
    __syncthreads();
    if (j < 5) {
      float acc = 0.f;
      for (int t = 0; t < 256; ++t) acc += We[j * HD + t] * weff[t];
      Wc[j * 12 + lh] = acc;
    } else if (j == 5) {
      float acc = 0.f;
      for (int t = 0; t < 256; ++t) acc += be_b[t] * weff[t];
      bc[lh] = acc;
    }
  } else {
    int bid = (blockIdx.x - 12) * 4 + (tid >> 6);  // l*128 + kt*16 + ntg
    int l = bid >> 7;
    int kt = (bid >> 4) & 7, ntg = bid & 15;
    int lane = tid & 63;
    const float* B = lin_w + (size_t)l * HD * HD;
    size_t base = ((size_t)bid * 64 + lane) * 8;
    int k0 = kt * 32 + (lane >> 4) * 8;
    int n = ((ntg >= 8) ? 128 : 0) + (lane & 15) * 8 + (ntg & 7);
#pragma unroll
    for (int j = 0; j < 8; ++j) {
      Bf_hi[base + j] = (_Float16)B[(size_t)(k0 + j) * HD + n];
    }
  }
}

// ---------------------------------------------------------------------------
// CSR scan kernels
// ---------------------------------------------------------------------------
__global__ __launch_bounds__(256) void tile_sums_kernel(
    const int* __restrict__ deg, int* __restrict__ tsum, int N) {
  __shared__ int red[256];
  int i = blockIdx.x * 256 + threadIdx.x;
  red[threadIdx.x] = (i < N) ? deg[i] : 0;
  __syncthreads();
  for (int off = 128; off > 0; off >>= 1) {
    if (threadIdx.x < off) red[threadIdx.x] += red[threadIdx.x + off];
    __syncthreads();
  }
  if (threadIdx.x == 0) tsum[blockIdx.x] = red[0];
}

__global__ __launch_bounds__(64) void scan_tsums_kernel(
    const int* __restrict__ tsum, int* __restrict__ toff, int T) {
  int lane = threadIdx.x;
  int carry = 0;
  for (int base = 0; base < T; base += 64) {
    int i = base + lane;
    int orig = (i < T) ? tsum[i] : 0;
    int v = orig;
#pragma unroll
    for (int off = 1; off < 64; off <<= 1) {
      int t = __shfl_up(v, off, 64);
      if (lane >= off) v += t;
    }
    if (i < T) toff[i] = carry + v - orig;
    carry += __shfl(v, 63, 64);
  }
}

__global__ __launch_bounds__(256) void scan_local_kernel(
    const int* __restrict__ deg, const int* __restrict__ toff,
    int* __restrict__ row_start, int N, int E) {
  __shared__ int buf[256];
  int i = blockIdx.x * 256 + threadIdx.x;
  int v = (i < N) ? deg[i] : 0;
  buf[threadIdx.x] = v;
  __syncthreads();
  for (int off = 1; off < 256; off <<= 1) {
    int t = (threadIdx.x >= off) ? buf[threadIdx.x - off] : 0;
    __syncthreads();
    buf[threadIdx.x] += t;
    __syncthreads();
  }
  if (i < N) row_start[i] = toff[blockIdx.x] + buf[threadIdx.x] - v;
  if (blockIdx.x == 0 && threadIdx.x == 0) row_start[N] = E;
}

// ---------------------------------------------------------------------------
// CSR scatter (R4 layout, best measured total): per edge, THREE 16B records
// into per-layer dense regions: word0 = src row, word1 = ae_h01, word2 =
// ae_h23, word3 pad. Scattered 16B writes cost write-allocate RMW, but the
// aggregate (runs 3x) gets dense 16B-stride reads — measured best mix
// (R4 483.6 vs R5 487.6 / R6 501).
// ---------------------------------------------------------------------------
__global__ __launch_bounds__(256) void scatter_csr_ae_kernel(
    const int* __restrict__ row, const int* __restrict__ col,
    const float* __restrict__ edge_attr, const int* __restrict__ row_start,
    int* __restrict__ cursor, const float* __restrict__ Wc,
    const float* __restrict__ bc, unsigned* __restrict__ ecsr, int E) {
  __shared__ float sWc[60];
  __shared__ float sbc[12];
  int t = threadIdx.x;
  if (t < 60) sWc[t] = Wc[t];
  if (t < 12) sbc[t] = bc[t];
  __syncthreads();
  int e = blockIdx.x * 256 + t;
  if (e >= E) return;
  int c = col[e];
  int p = atomicAdd(&cursor[c], 1);
  float ea[5];
#pragma unroll
  for (int k = 0; k < 5; ++k) ea[k] = edge_attr[(size_t)e * 5 + k];
  unsigned r0 = (unsigned)row[e];
  int slot = row_start[c] + p;
  size_t E4 = (size_t)E * 4;  // layer stride in unsigned words
#pragma unroll
  for (int l = 0; l < NLAYER; ++l) {
    float av[NHEAD];
#pragma unroll
    for (int hh = 0; hh < NHEAD; ++hh) {
      int lh = l * NHEAD + hh;
      float s = sbc[lh];
#pragma unroll
      for (int k = 0; k < 5; ++k) s += ea[k] * sWc[k * 12 + lh];
      av[hh] = s;
    }
    __half2 p0 = __floats2half2_rn(av[0], av[1]);
    __half2 p1 = __floats2half2_rn(av[2], av[3]);
    uint4v v = {r0, *(unsigned*)&p0, *(unsigned*)&p1, 0u};
    *(uint4v*)(ecsr + l * E4 + (size_t)slot * 4) = v;
  }
}

// ---------------------------------------------------------------------------
// MFMA GEMM — R7 restructure: stage the ENTIRE B-half (8 kt x 8KB = 64KB)
// in LDS once with a single barrier, then a BARRIER-FREE K-loop: per kt one
// global half8 A-load + 8 ds_read_b128 + 8 MFMA, pipelineable across kt.
// (Old structure: 2 barriers x 8 kt with a global load between them — the
// whole 8-wave block serialized stage->barrier->load->compute 16x.)
// 64KB LDS -> 2 blocks/CU = 16 waves/CU.
// ---------------------------------------------------------------------------
__global__ __launch_bounds__(512) void mfma_gemm_fused_kernel(
    const _Float16* __restrict__ A, const _Float16* __restrict__ Bf_hi,
    const float* __restrict__ att_s, const float* __restrict__ att_d,
    __half* __restrict__ xh_h, float* __restrict__ a_src,
    float* __restrict__ a_dst, int N) {
  __shared__ _Float16 sBh[32768];  // 64 KB: all 8 kt-slices of this col half
  const int tid = threadIdx.x;
  const int wave = tid >> 6, lane = tid & 63;
  const int m = lane & 15, quad = lane >> 4;
  const int y = blockIdx.y;
  const int rowbase = blockIdx.x * 128 + wave * 16;
  const int arow = rowbase + m;
  const int arowc = (arow < N) ? arow : (N - 1);

  // one-shot stage: 8 x 8KB
#pragma unroll
  for (int kt = 0; kt < 8; ++kt) {
    const float4* gh = (const float4*)(Bf_hi + ((size_t)kt * 16 + y * 8) * 512);
    ((float4*)sBh)[kt * 512 + tid] = gh[tid];
  }

  float4v acc[8];
#pragma unroll
  for (int nt = 0; nt < 8; ++nt) acc[nt] = (float4v){0.f, 0.f, 0.f, 0.f};

  __syncthreads();  // staging complete — the ONLY barrier

#pragma unroll
  for (int kt = 0; kt < 8; ++kt) {
    half8 a = *(const half8*)(A + (size_t)arowc * HD + kt * 32 + quad * 8);
#pragma unroll
    for (int nt = 0; nt < 8; ++nt) {
      half8 bhi = *(const half8*)&sBh[kt * 4096 + nt * 512 + lane * 8];
      acc[nt] = __builtin_amdgcn_mfma_f32_16x16x32_f16(a, bhi, acc[nt], 0, 0, 0);
    }
  }

  // lane's 8 cols: y*128 + m*8 + nt — all in head hh = y*2 + (m>>3)
  const int hh = y * 2 + (m >> 3);
  const int colbase = y * 128 + m * 8;
  float ats[8], atd[8];
#pragma unroll
  for (int nt = 0; nt < 8; ++nt) {
    ats[nt] = att_s[colbase + nt];
    atd[nt] = att_d[colbase + nt];
  }
  _Float16* xf = (_Float16*)xh_h;
#pragma unroll
  for (int r = 0; r < 4; ++r) {
    int orow = rowbase + quad * 4 + r;
    bool valid = orow < N;
    float ps = 0.f, pd = 0.f;
    half8 h0;
#pragma unroll
    for (int nt = 0; nt < 8; ++nt) {
      h0[nt] = (_Float16)acc[nt][r];
      ps += acc[nt][r] * ats[nt];
      pd += acc[nt][r] * atd[nt];
    }
    if (valid) {
      *(half8*)(xf + (size_t)orow * HD + colbase) = h0;
    }
    ps += __shfl_xor(ps, 1, 64);
    ps += __shfl_xor(ps, 2, 64);
    ps += __shfl_xor(ps, 4, 64);
    pd += __shfl_xor(pd, 1, 64);
    pd += __shfl_xor(pd, 2, 64);
    pd += __shfl_xor(pd, 4, 64);
    if (valid && (m & 7) == 0) {
      a_src[(size_t)orow * NHEAD + hh] = ps;
      a_dst[(size_t)orow * NHEAD + hh] = pd;
    }
  }
}

// ---------------------------------------------------------------------------
// SINGLE-PASS fused softmax + gather-aggregate, 2 nodes/wave (lanes 0-31 =
// node A, 32-63 = node B; 8 ch/lane). R4 structure (best: 67.5us, VALU 56%):
// ZERO cross-lane ops in the inner loop; dense per-layer 16B records
// (uniform dwordx4 per edge → TA broadcast); all 8 weights computed
// locally per lane.
// ---------------------------------------------------------------------------
__global__ __launch_bounds__(256) void fused_aggregate_kernel(
    const __half* __restrict__ xh_h, const unsigned* __restrict__ elay,
    const int* __restrict__ row_start,
    const float* __restrict__ a_src, const float* __restrict__ a_dst,
    const float* __restrict__ cb, const float* __restrict__ gm,
    const float* __restrict__ bt, float inv_std, _Float16* __restrict__ hout,
    int N) {
  const int tid = threadIdx.x;
  const int lane = tid & 63;
  const int wave = tid >> 6;
  const int halfw = lane >> 5;      // 0: node A, 1: node B
  const int l32 = lane & 31;        // index within half-wave
  const int hw = l32 >> 3;          // head 0..3
  const int chb = l32 * 8;          // channel base (8 ch per lane)
  const char* __restrict__ xb = (const char*)xh_h;
  const char* __restrict__ eb = (const char*)elay;
  const char* __restrict__ ab = (const char*)a_src;
  const bool hi_half = (hw & 1);
  const int awsel = (hw >> 1);      // 0 → word1 (heads 0,1), 1 → word2 (heads 2,3)

  int n = blockIdx.x * 8 + wave * 2 + halfw;
  bool valid = n < N;
  int nc = valid ? n : (N - 1);

  int s = row_start[nc];
  int e = row_start[nc + 1];
  if (!valid) e = s;

  // self row (8 ch = 16B) + dst logit — issued early
  half8 sv = *(const half8*)(xb + ((unsigned)nc << 9) + ((unsigned)l32 << 4));
  float based = a_dst[(size_t)nc * 4 + hw];

  float acc[8];
#pragma unroll
  for (int k = 0; k < 8; ++k) acc[k] = 0.f;
  float zpart = 0.f, aepart = 0.f;

  for (int chunk = s; chunk < e; chunk += 8) {
    // 8 record loads (16B each; uniform address within half-wave)
    uint4v rc[8];
#pragma unroll
    for (int u = 0; u < 8; ++u) {
      int ed = chunk + u;
      ed = (ed < e) ? ed : (e - 1);   // clamp: stays within [s,e)
      rc[u] = *(const uint4v*)(eb + ((size_t)(unsigned)ed << 4));
    }
    unsigned rows[8], aw[8];
#pragma unroll
    for (int u = 0; u < 8; ++u) {
      rows[u] = rc[u][0];
      aw[u] = awsel ? rc[u][2] : rc[u][1];
    }
    // 8 channel gathers (16B/lane, 512B per half-wave) — independent of the
    // weight chain below; both ladders stay in flight together.
    half8 xr[8];
#pragma unroll
    for (int u = 0; u < 8; ++u)
      xr[u] = *(const half8*)(xb + (((size_t)rows[u] << 9) +
                                    ((unsigned)l32 << 4)));
    // weights: each lane computes all 8 locally (no broadcast needed)
    float w[8];
#pragma unroll
    for (int u = 0; u < 8; ++u) {
      __half2 h2 = *(__half2*)&aw[u];
      float ae = hi_half ? __high2float(h2) : __low2float(h2);
      float as_ = *(const float*)(ab + ((size_t)rows[u] << 4) +
                                  ((unsigned)hw << 2));
      float lg = as_ + based + ae;
      lg = (lg >= 0.f) ? lg : NEG_SLOPE * lg;
      float ww = __expf(lg);
      bool mv = (chunk + u) < e;
      ww = mv ? ww : 0.f;
      ae = mv ? ae : 0.f;
      zpart += ww;
      aepart += ae;
      w[u] = ww;
    }
    // consume
#pragma unroll
    for (int u = 0; u < 8; ++u) {
#pragma unroll
      for (int k = 0; k < 8; ++k) acc[k] += w[u] * (float)xr[u][k];
    }
  }

  float dinv = (e > s) ? 1.0f / (float)(e - s) : 1.0f;
  float sl = *(const float*)(ab + ((unsigned)nc << 4) + ((unsigned)hw << 2))
             + based + aepart * dinv;
  sl = (sl >= 0.f) ? sl : NEG_SLOPE * sl;
  float wself = __expf(sl);
#pragma unroll
  for (int k = 0; k < 8; ++k) acc[k] += wself * (float)sv[k];
  float zinv = 1.0f / (zpart + wself + 1e-16f);

  if (valid) {
    half8 ho;
#pragma unroll
    for (int k = 0; k < 8; ++k) {
      float gsk = gm[chb + k] * inv_std;
      float ofk = cb[chb + k] * gsk + bt[chb + k];
      ho[k] = (_Float16)fmaxf(acc[k] * zinv * gsk + ofk, 0.f);
    }
    *(half8*)&hout[(size_t)n * HD + chb] = ho;
  }
}

// ---------------------------------------------------------------------------
// Global mean pool over sorted batch ids (h fp16). One block per graph,
// half2 loads + 4-deep independent accumulators.
// ---------------------------------------------------------------------------
__global__ __launch_bounds__(128) void pool_kernel(
    const _Float16* __restrict__ h, const int* __restrict__ batch,
    float* __restrict__ out, int N) {
  int g = blockIdx.x;
  int tid = threadIdx.x;
  __shared__ int s_lo, s_hi;
  if (tid == 0) {
    int lo = 0, hi = N;
    while (lo < hi) { int mid = (lo + hi) >> 1; if (batch[mid] < g) lo = mid + 1; else hi = mid; }
    s_lo = lo;
    lo = 0; hi = N;
    while (lo < hi) { int mid = (lo + hi) >> 1; if (batch[mid] < g + 1) lo = mid + 1; else hi = mid; }
    s_hi = lo;
  }
  __syncthreads();
  int lo = s_lo, hi = s_hi;
  const __half2* h2 = (const __half2*)h;  // N rows x 128 half2
  float a0 = 0.f, b0 = 0.f, a1 = 0.f, b1 = 0.f;
  float a2 = 0.f, b2 = 0.f, a3 = 0.f, b3 = 0.f;
  int n = lo;
  for (; n + 4 <= hi; n += 4) {
    __half2 v0 = h2[(size_t)(n + 0) * 128 + tid];
    __half2 v1 = h2[(size_t)(n + 1) * 128 + tid];
    __half2 v2 = h2[(size_t)(n + 2) * 128 + tid];
    __half2 v3 = h2[(size_t)(n + 3) * 128 + tid];
    a0 += __low2float(v0); b0 += __high2float(v0);
    a1 += __low2float(v1); b1 += __high2float(v1);
    a2 += __low2float(v2); b2 += __high2float(v2);
    a3 += __low2float(v3); b3 += __high2float(v3);
  }
  for (; n < hi; ++n) {
    __half2 v = h2[(size_t)n * 128 + tid];
    a0 += __low2float(v); b0 += __high2float(v);
  }
  float sa = (a0 + a1) + (a2 + a3);
  float sb = (b0 + b1) + (b2 + b3);
  int cnt = hi - lo;
  float inv = 1.0f / (float)(cnt > 0 ? cnt : 1);
  float2 o;
  o.x = sa * inv;
  o.y = sb * inv;
  *(float2*)&out[(size_t)g * HD + tid * 2] = o;
}

// ---------------------------------------------------------------------------
extern "C" void kernel_launch(void* const* d_in, const int* in_sizes, int n_in,
                              void* d_out, int out_size, void* d_ws, size_t ws_size,
                              hipStream_t stream) {
  const float* x = (const float*)d_in[0];
  const int* ei = (const int*)d_in[1];
  const float* edge_attr = (const float*)d_in[2];
  const int* batch = (const int*)d_in[3];
  const float* Wn = (const float*)d_in[4];
  const float* bn_b = (const float*)d_in[5];
  const float* We = (const float*)d_in[6];
  const float* be_b = (const float*)d_in[7];
  const float* lin_w = (const float*)d_in[8];
  const float* att_src = (const float*)d_in[9];
  const float* att_dst = (const float*)d_in[10];
  const float* lin_edge_w = (const float*)d_in[11];
  const float* att_edge = (const float*)d_in[12];
  const float* conv_bias = (const float*)d_in[13];
  const float* gamma = (const float*)d_in[14];
  const float* beta = (const float*)d_in[15];

  const int N = in_sizes[3];
  const int E = in_sizes[1] / 2;
  const int G = out_size / HD;
  const int* row = ei;
  const int* col = ei + E;

  char* ws = (char*)d_ws;
  size_t off = 0;
  auto alloc = [&](size_t bytes) -> char* {
    char* p = ws + off;
    off += (bytes + 255) & ~(size_t)255;
    return p;
  };
  _Float16* h = (_Float16*)alloc((size_t)N * HD * 2);
  __half* xh_h = (__half*)alloc((size_t)N * HD * 2);
  float* a_src = (float*)alloc((size_t)N * NHEAD * 4);
  float* a_dst = (float*)alloc((size_t)N * NHEAD * 4);
  unsigned* ecsr = (unsigned*)alloc((size_t)E * 16 * NLAYER);  // 16B/edge/layer
  int* deg = (int*)alloc((size_t)N * 4);
  int* row_start = (int*)alloc((size_t)(N + 1) * 4);
  int* cursor = (int*)alloc((size_t)N * 4);
  int* tsum = (int*)alloc(4096);
  int* toff = (int*)alloc(4096);
  float* Wc = (float*)alloc(64 * 4);
  float* bc = (float*)alloc(16 * 4);
  _Float16* Bf_hi = (_Float16*)alloc((size_t)NLAYER * HD * HD * 2);

  (void)hipMemsetAsync(deg, 0, (size_t)N * 4, stream);
  (void)hipMemsetAsync(cursor, 0, (size_t)N * 4, stream);

  int embedBlocks = (N + 7) / 8;
  int countBlocks = (E + 255) / 256;
  embed_count_kernel<<<embedBlocks + countBlocks, 256, 0, stream>>>(
      x, Wn, bn_b, h, N, col, deg, E, embedBlocks);
  wc_bfrag_kernel<<<12 + NLAYER * 32, 256, 0, stream>>>(
      lin_edge_w, att_edge, We, be_b, Wc, bc, lin_w, Bf_hi);
  int T = (N + 255) / 256;
  tile_sums_kernel<<<T, 256, 0, stream>>>(deg, tsum, N);
  scan_tsums_kernel<<<1, 64, 0, stream>>>(tsum, toff, T);
  scan_local_kernel<<<T, 256, 0, stream>>>(deg, toff, row_start, N, E);
  scatter_csr_ae_kernel<<<(E + 255) / 256, 256, 0, stream>>>(
      row, col, edge_attr, row_start, cursor, Wc, bc, ecsr, E);

  const float inv_std = 1.0f / sqrtf(1.0f + 1e-5f);
  for (int l = 0; l < NLAYER; ++l) {
    dim3 gg((N + 127) / 128, 2);
    mfma_gemm_fused_kernel<<<gg, 512, 0, stream>>>(
        h, Bf_hi + (size_t)l * HD * HD,
        att_src + l * HD, att_dst + l * HD, xh_h, a_src, a_dst, N);
    fused_aggregate_kernel<<<(N + 7) / 8, 256, 0, stream>>>(
        xh_h, ecsr + (size_t)l * E * 4, row_start, a_src, a_dst,
        conv_bias + l * HD, gamma + l * HD, beta + l * HD, inv_std, h, N);
  }
  pool_kernel<<<G, 128, 0, stream>>>(h, batch, (float*)d_out, N);
}